// Round 1
// baseline (251.211 us; speedup 1.0000x reference)
//
#include <hip/hip_runtime.h>
#include <hip/hip_bf16.h>

#define BN   64
#define CIN  512
#define COUT 512
#define HW   784
#define NT   128
#define MT   112
#define BK   64
#define SW_STRIDE 72   /* bf16 units, 144 B rows (16B-aligned, bank-step 4) */
#define SX_STRIDE 64   /* bf16 units, swizzled granules */

typedef __attribute__((ext_vector_type(8))) short short8;
typedef __attribute__((ext_vector_type(4))) float f32x4;

__device__ __forceinline__ unsigned short f2bf(float f) {
    union { float f; unsigned int u; } v; v.f = f;
    unsigned int r = v.u + 0x7fffu + ((v.u >> 16) & 1u);   // RNE
    return (unsigned short)(r >> 16);
}

__device__ __forceinline__ uint2 pack4(float a, float b, float c, float d) {
    uint2 r;
    r.x = (unsigned int)f2bf(a) | ((unsigned int)f2bf(b) << 16);
    r.y = (unsigned int)f2bf(c) | ((unsigned int)f2bf(d) << 16);
    return r;
}

__global__ void wconv_kernel(const float* __restrict__ W, unsigned short* __restrict__ Wb) {
    int i = (blockIdx.x * 256 + threadIdx.x) * 8;
    float4 a = *(const float4*)(W + i);
    float4 b = *(const float4*)(W + i + 4);
    uint2 lo = pack4(a.x, a.y, a.z, a.w);
    uint2 hi = pack4(b.x, b.y, b.z, b.w);
    uint4 v; v.x = lo.x; v.y = lo.y; v.z = hi.x; v.w = hi.y;
    *(uint4*)(Wb + i) = v;
}

template<bool PREW>
__global__ __launch_bounds__(256, 2)
void shiftconv_kernel(const float* __restrict__ x,
                      const void* __restrict__ Wp,
                      const float* __restrict__ gamma,
                      const float* __restrict__ beta,
                      const float* __restrict__ rmean,
                      const float* __restrict__ rvar,
                      float* __restrict__ out)
{
    __shared__ unsigned short sW[NT * SW_STRIDE];   // 18432 B
    __shared__ unsigned short sX[MT * SX_STRIDE];   // 14336 B

    const int t = threadIdx.x;
    const int ot = blockIdx.x;           // fastest: 4 o-tiles share an X-tile (L2/L3 locality)
    const int mt = blockIdx.y;
    const int b  = blockIdx.z;
    const int o_base  = ot * NT;
    const int hw_base = mt * MT;
    const float* xb = x + (size_t)b * CIN * HW;

    const int lane = t & 63;
    const int wv   = t >> 6;
    const int m16  = lane & 15;
    const int q    = lane >> 4;

    f32x4 acc[2][7];
    #pragma unroll
    for (int i = 0; i < 2; ++i)
        #pragma unroll
        for (int j = 0; j < 7; ++j)
            acc[i][j] = (f32x4){0.f, 0.f, 0.f, 0.f};

    #pragma unroll
    for (int kk = 0; kk < CIN / BK; ++kk) {
        const int k0 = kk * BK;
        const int g  = k0 >> 7;          // compile-time per unrolled iter: shift group

        // ---- stage X: shift-gather + 4x4 transpose + fp32->bf16 ----
        #pragma unroll
        for (int e0 = 0; e0 < 2; ++e0) {
            int e = t + e0 * 256;
            if (e < (BK / 4) * (MT / 4)) {           // 448 4c x 4m blocks
                int cq = e / 28;
                int mq = e - cq * 28;
                int hw = hw_base + mq * 4;
                const float* src = xb + (size_t)(k0 + cq * 4) * HW;
                float4 v0, v1, v2, v3;
                if (g < 2) {
                    // roll along h: hw' = (hw +- 28) mod 784, float4-exact
                    int shw = hw + (g == 0 ? 28 : HW - 28);
                    if (shw >= HW) shw -= HW;
                    v0 = *(const float4*)(src + 0 * HW + shw);
                    v1 = *(const float4*)(src + 1 * HW + shw);
                    v2 = *(const float4*)(src + 2 * HW + shw);
                    v3 = *(const float4*)(src + 3 * HW + shw);
                } else {
                    // roll along w: aligned float4 + neighbor scalar + shuffle
                    int h  = hw / 28;
                    int w0 = hw - h * 28;
                    int base = h * 28;
                    #pragma unroll
                    for (int j = 0; j < 4; ++j) {
                        const float* row = src + j * HW + base;
                        float4 a = *(const float4*)(row + w0);
                        float4 r;
                        if (g == 2) {
                            float ex = row[(w0 + 4 < 28) ? (w0 + 4) : 0];
                            r.x = a.y; r.y = a.z; r.z = a.w; r.w = ex;
                        } else {
                            float ex = row[(w0 == 0) ? 27 : (w0 - 1)];
                            r.x = ex; r.y = a.x; r.z = a.y; r.w = a.z;
                        }
                        if (j == 0) v0 = r; else if (j == 1) v1 = r;
                        else if (j == 2) v2 = r; else v3 = r;
                    }
                }
                int m0 = mq * 4;
                // swizzled granule writes: p = (c_granule + 5*m) & 15
                { int p = (cq + 5 * (m0 + 0)) & 15;
                  *(uint2*)(&sX[(m0 + 0) * SX_STRIDE + p * 4]) = pack4(v0.x, v1.x, v2.x, v3.x); }
                { int p = (cq + 5 * (m0 + 1)) & 15;
                  *(uint2*)(&sX[(m0 + 1) * SX_STRIDE + p * 4]) = pack4(v0.y, v1.y, v2.y, v3.y); }
                { int p = (cq + 5 * (m0 + 2)) & 15;
                  *(uint2*)(&sX[(m0 + 2) * SX_STRIDE + p * 4]) = pack4(v0.z, v1.z, v2.z, v3.z); }
                { int p = (cq + 5 * (m0 + 3)) & 15;
                  *(uint2*)(&sX[(m0 + 3) * SX_STRIDE + p * 4]) = pack4(v0.w, v1.w, v2.w, v3.w); }
            }
        }

        // ---- stage W ----
        if (PREW) {
            const unsigned short* Wb = (const unsigned short*)Wp;
            #pragma unroll
            for (int i = 0; i < 4; ++i) {
                int e  = t + i * 256;                 // 1024 granules of 8 bf16
                int ol = e >> 3;
                int kg = (e & 7) * 8;
                uint4 v = *(const uint4*)(Wb + (size_t)(o_base + ol) * CIN + k0 + kg);
                *(uint4*)(&sW[ol * SW_STRIDE + kg]) = v;
            }
        } else {
            const float* Wf = (const float*)Wp;
            #pragma unroll
            for (int i = 0; i < 4; ++i) {
                int e  = t + i * 256;
                int ol = e >> 3;
                int kg = (e & 7) * 8;
                const float* wr = Wf + (size_t)(o_base + ol) * CIN + k0 + kg;
                float4 a = *(const float4*)(wr);
                float4 c = *(const float4*)(wr + 4);
                uint2 lo = pack4(a.x, a.y, a.z, a.w);
                uint2 hi = pack4(c.x, c.y, c.z, c.w);
                uint4 v; v.x = lo.x; v.y = lo.y; v.z = hi.x; v.w = hi.y;
                *(uint4*)(&sW[ol * SW_STRIDE + kg]) = v;
            }
        }

        __syncthreads();

        // ---- compute: 2 k-steps of 32 ----
        #pragma unroll
        for (int ks = 0; ks < BK; ks += 32) {
            short8 afrag[2];
            #pragma unroll
            for (int bo = 0; bo < 2; ++bo) {
                int row = wv * 32 + bo * 16 + m16;
                afrag[bo] = *(const short8*)(&sW[row * SW_STRIDE + ks + q * 8]);
            }
            #pragma unroll
            for (int bm = 0; bm < 7; ++bm) {
                int m  = bm * 16 + m16;
                int g0 = (ks >> 2) + 2 * q;
                int p0 = (g0 + 5 * m) & 15;
                int p1 = (g0 + 1 + 5 * m) & 15;
                uint2 lo = *(const uint2*)(&sX[m * SX_STRIDE + p0 * 4]);
                uint2 hi = *(const uint2*)(&sX[m * SX_STRIDE + p1 * 4]);
                union { uint2 u2[2]; short8 s; } fb;
                fb.u2[0] = lo; fb.u2[1] = hi;
                acc[0][bm] = __builtin_amdgcn_mfma_f32_16x16x32_bf16(afrag[0], fb.s, acc[0][bm], 0, 0, 0);
                acc[1][bm] = __builtin_amdgcn_mfma_f32_16x16x32_bf16(afrag[1], fb.s, acc[1][bm], 0, 0, 0);
            }
        }
        __syncthreads();
    }

    // ---- epilogue: folded BN + ReLU, NT stores ----
    float scl[2][4], shf[2][4];
    #pragma unroll
    for (int bo = 0; bo < 2; ++bo)
        #pragma unroll
        for (int r = 0; r < 4; ++r) {
            int o = o_base + wv * 32 + bo * 16 + q * 4 + r;
            float sc = gamma[o] * rsqrtf(rvar[o] + 1e-5f);
            scl[bo][r] = sc;
            shf[bo][r] = beta[o] - rmean[o] * sc;
        }
    float* outb = out + (size_t)b * COUT * HW;
    #pragma unroll
    for (int bo = 0; bo < 2; ++bo) {
        #pragma unroll
        for (int r = 0; r < 4; ++r) {
            int o = o_base + wv * 32 + bo * 16 + q * 4 + r;
            float* orow = outb + (size_t)o * HW + hw_base + m16;
            #pragma unroll
            for (int bm = 0; bm < 7; ++bm) {
                float y = acc[bo][bm][r] * scl[bo][r] + shf[bo][r];
                y = fmaxf(y, 0.f);
                __builtin_nontemporal_store(y, orow + bm * 16);
            }
        }
    }
}

extern "C" void kernel_launch(void* const* d_in, const int* in_sizes, int n_in,
                              void* d_out, int out_size, void* d_ws, size_t ws_size,
                              hipStream_t stream)
{
    const float* x     = (const float*)d_in[0];
    const float* W     = (const float*)d_in[1];
    const float* gamma = (const float*)d_in[2];
    const float* beta  = (const float*)d_in[3];
    const float* rmean = (const float*)d_in[4];
    const float* rvar  = (const float*)d_in[5];
    float* out = (float*)d_out;

    dim3 grid(COUT / NT, HW / MT, BN);   // (4, 7, 64) = 1792 blocks
    if (ws_size >= (size_t)(COUT * CIN * 2)) {
        wconv_kernel<<<COUT * CIN / (256 * 8), 256, 0, stream>>>(W, (unsigned short*)d_ws);
        shiftconv_kernel<true><<<grid, 256, 0, stream>>>(x, d_ws, gamma, beta, rmean, rvar, out);
    } else {
        shiftconv_kernel<false><<<grid, 256, 0, stream>>>(x, (const void*)W, gamma, beta, rmean, rvar, out);
    }
}